// Round 9
// baseline (25195.425 us; speedup 1.0000x reference)
//
#include <hip/hip_runtime.h>
#include <math.h>

static constexpr int T_SEQ = 1024;
static constexpr int DIN = 128;
static constexpr int HID = 256;
static constexpr int DOUT = 1000;
static constexpr int NB = 128;
static constexpr int SLOT = HID * NB;   // 32768 floats per h slot, [H][B]-major

// LDS layout (floats).
static constexpr int W1STR = 388;              // K=384 + 4
static constexpr int W2STR = 516;              // K=512 + 4
static constexpr int ASTR  = 652;              // [x 0:128 | h1 128:384 | h2 384:640] + 12
static constexpr int OFF_W2 = 16 * W1STR;            // 6208
static constexpr int OFF_A  = OFF_W2 + 16 * W2STR;   // 14464
static constexpr int OFF_B1 = OFF_A + 32 * ASTR;     // 35328
static constexpr int OFF_B2 = OFF_B1 + 16;           // 35344
static constexpr size_t SMEM_BYTES = (size_t)(OFF_B2 + 16) * 4;   // 141,440 B (1 block/CU)

typedef float v4f __attribute__((ext_vector_type(4)));
typedef unsigned long long u64t;

#define SCOPE_AGENT __HIP_MEMORY_SCOPE_AGENT

__device__ __forceinline__ int ld_flag(const int* p) {
    return __hip_atomic_load(p, __ATOMIC_RELAXED, SCOPE_AGENT);
}
__device__ __forceinline__ void st_flag(int* p, int v) {
    __hip_atomic_store(p, v, __ATOMIC_RELAXED, SCOPE_AGENT);
}
// write-through 8B store to the coherence point (producer side). R16 packs
// publish pairs into u64 — halves CP store transactions on the drain path.
__device__ __forceinline__ void st_cp8(u64t* p, u64t v) {
    __hip_atomic_store(p, v, __ATOMIC_RELAXED, SCOPE_AGENT);
}
// R13 (proven): 8B coherence-point LOAD (cache-bypass). Fence-free
// protocol: publishes write-through, consumers read the coherence point,
// flags ordered by waitcnt(0)+B4.
__device__ __forceinline__ u64t ld_cp8(const u64t* p) {
    return __hip_atomic_load(p, __ATOMIC_RELAXED, SCOPE_AGENT);
}

union F2U { u64t u; float f[2]; };

__device__ __forceinline__ float dot4(float acc, v4f va, v4f vb) {
    return fmaf(va.x, vb.x, fmaf(va.y, vb.y,
           fmaf(va.z, vb.z, fmaf(va.w, vb.w, acc))));
}

// GEMM tile: 8 batches x 4 cols per thread, k-split 16 within the wave,
// lane = ks(bits0-3) | cq(bits4-5); wave-in-half = batch-oct bo.
// Monolithic k-range again (R15's split forced acc to live across
// barriers -> spills; reverted). A in two groups of 4 (R14).
template<int NCHUNK, int WSTR>
__device__ __forceinline__ void gemm_tile(float acc[8][4],
                                          const float* __restrict__ Ab,
                                          const float* __restrict__ Wb,
                                          const int ks)
{
    #pragma unroll
    for (int j = 0; j < NCHUNK; ++j) {
        const int ko = (j * 16 + ks) * 4;
        v4f w[4];
        #pragma unroll
        for (int c = 0; c < 4; ++c) w[c] = *(const v4f*)(Wb + c * WSTR + ko);
        {
            v4f a4[4];
            #pragma unroll
            for (int i = 0; i < 4; ++i) a4[i] = *(const v4f*)(Ab + i * ASTR + ko);
            #pragma unroll
            for (int i = 0; i < 4; ++i)
                #pragma unroll
                for (int c = 0; c < 4; ++c)
                    acc[i][c] = dot4(acc[i][c], a4[i], w[c]);
        }
        {
            v4f a4[4];
            #pragma unroll
            for (int i = 0; i < 4; ++i) a4[i] = *(const v4f*)(Ab + (i + 4) * ASTR + ko);
            #pragma unroll
            for (int i = 0; i < 4; ++i)
                #pragma unroll
                for (int c = 0; c < 4; ++c)
                    acc[i + 4][c] = dot4(acc[i + 4][c], a4[i], w[c]);
        }
    }
}

// Fold-reduce acc over the 16 ks lanes with ownership halving
// (xor4 -> xor2 -> xor1 -> xor8). Lane ks ends owning the COMPLETE z
// (4 gates) for batch bo*8+(ks&7), unit cq; ew + state update in
// registers. R16: publish PACKED — even ks<8 lanes store {hv, neighbor}
// as one 8B CP store. All indices compile-time (rule 20).
__device__ __forceinline__ void reduce_ew_publish(float acc[8][4], const int ks,
    const float b_i, const float b_f, const float b_g, const float b_o,
    float& cst, float* __restrict__ hb)
{
    #pragma unroll
    for (int i = 0; i < 8; ++i)
        #pragma unroll
        for (int c = 0; c < 4; ++c)
            acc[i][c] += __shfl_xor(acc[i][c], 4);
    float s1[4][4];
    const bool kb2 = (ks & 4) != 0;
    #pragma unroll
    for (int i = 0; i < 4; ++i)
        #pragma unroll
        for (int c = 0; c < 4; ++c)
            s1[i][c] = kb2 ? acc[i + 4][c] : acc[i][c];
    #pragma unroll
    for (int i = 0; i < 4; ++i)
        #pragma unroll
        for (int c = 0; c < 4; ++c)
            s1[i][c] += __shfl_xor(s1[i][c], 2);
    float s2[2][4];
    const bool kb1 = (ks & 2) != 0;
    #pragma unroll
    for (int i = 0; i < 2; ++i)
        #pragma unroll
        for (int c = 0; c < 4; ++c)
            s2[i][c] = kb1 ? s1[i + 2][c] : s1[i][c];
    #pragma unroll
    for (int i = 0; i < 2; ++i)
        #pragma unroll
        for (int c = 0; c < 4; ++c)
            s2[i][c] += __shfl_xor(s2[i][c], 1);
    float z4[4];
    const bool kb0 = (ks & 1) != 0;
    #pragma unroll
    for (int c = 0; c < 4; ++c)
        z4[c] = kb0 ? s2[1][c] : s2[0][c];
    #pragma unroll
    for (int c = 0; c < 4; ++c)
        z4[c] += __shfl_xor(z4[c], 8);

    const float zi = z4[0] + b_i, zf = z4[1] + b_f;
    const float zg = z4[2] + b_g, zo = z4[3] + b_o;
    const float ig = 1.f / (1.f + expf(-zi));
    const float fg = 1.f / (1.f + expf(-zf));
    const float gg = fmaxf(zg, 0.f);
    const float og = 1.f / (1.f + expf(-zo));
    cst = fg * cst + ig * gg;
    const float hv = og * fmaxf(cst, 0.f);
    F2U pk; pk.f[0] = hv; pk.f[1] = __shfl_xor(hv, 1);
    if ((ks & 9) == 0)                       // even ks < 8
        st_cp8((u64t*)(hb + ks), pk.u);      // hb+ks even -> 8B aligned
}

// Fused 2-layer LSTM, 256 blocks x 512 threads, 1 block/CU (LDS 141.4 KB).
// R16 restructure: PER-WAVE self-sufficiency, ONE barrier per phase.
//   - every wave polls all 64 group flags itself (coalesced 256B read);
//   - each wave stages ONLY its own 8 batch-rows of the A-panel:
//       L1 wave bo: x rows (cached) + h1 cols 128:384 (CP loads)
//       L2 wave bo: h1 cols 128:384 + h2 cols 384:640 (CP loads)
//     h1 rows are staged TWICE (L1 & L2 wave pair) with IDENTICAL values
//     — benign LDS same-value race; each wave waits only on its OWN
//     lgkmcnt(0), so no cross-wave staging barrier is needed;
//   - wave GEMMs immediately after its own stage; publishes; then the
//     single B4 (cross-phase hsA write/read separation + flag ordering).
// R15's lesson honored: acc never lives across a barrier (no spills);
// lockstep-period arithmetic honored: this removes serialization
// (B1+B2+wave0-poll convergence), not just work placement.
__global__ __launch_bounds__(512)
void lstm_fused_kernel(const float* __restrict__ x,
                       const float* __restrict__ W1, const float* __restrict__ U1,
                       const float* __restrict__ b1,
                       const float* __restrict__ W2, const float* __restrict__ U2,
                       const float* __restrict__ b2,
                       float* __restrict__ h1b,   // 2*SLOT (d_out scratch), [slot][H][B]
                       float* __restrict__ ws)    // [1024 ints: flags][2*SLOT h2 [H][B]]
{
    extern __shared__ float smem[];
    float* wT1  = smem;
    float* wT2  = smem + OFF_W2;
    float* hsA  = smem + OFF_A;
    float* bia1 = smem + OFF_B1;
    float* bia2 = smem + OFF_B2;

    int*   F   = (int*)ws;          // 4 groups x 128 ints (first 64 used each)
    float* h2b = ws + 1024;

    const int tid = threadIdx.x;
    const int bid = blockIdx.x;
    const int bg  = bid >> 6;       // batch group 0..3 (batches bg*32..+31)
    const int ug  = bid & 63;       // unit group (units ug*4..+3)
    int* grpF = F + bg * 128;
    int* myF  = grpF + ug;

    const int lane = tid & 63;
    const int ks   = lane & 15;     // in-wave k-split index
    const int cq   = lane >> 4;     // col quad = unit 0..3
    const int half = tid >> 8;      // 0: L1 waves, 1: L2 waves
    const int bo   = (tid >> 6) & 3;// wave-in-half = batch oct

    // ---- one-time: both weight tiles (transposed) + biases into LDS ----
    {
        const int hf = tid >> 8;
        const int t  = tid & 255;
        const int K    = hf ? 512 : 384;
        const int len0 = hf ? 256 : 128;
        const float* Wp = hf ? W2 : W1;
        const float* Up = hf ? U2 : U1;
        float* wt = hf ? wT2 : wT1;
        const int wstr = hf ? W2STR : W1STR;
        for (int c = 0; c < 16; ++c) {
            const int col = (c & 3) * HID + ug * 4 + (c >> 2);   // gate-major
            for (int k = t; k < K; k += 256)
                wt[c * wstr + k] = (k < len0) ? Wp[(size_t)k * (4 * HID) + col]
                                              : Up[(size_t)(k - len0) * (4 * HID) + col];
        }
    }
    if (tid < 16)                     bia1[tid] = b1[(tid & 3) * HID + ug * 4 + (tid >> 2)];
    else if (tid >= 256 && tid < 272) { const int t = tid - 256;
                                        bia2[t]  = b2[(t & 3) * HID + ug * 4 + (t >> 2)]; }
    __syncthreads();

    // per-thread persistent state: bias regs (constant all phases) + cell st
    const float* biap = half ? bia2 : bia1;
    const float b_i = biap[cq * 4 + 0], b_f = biap[cq * 4 + 1];
    const float b_g = biap[cq * 4 + 2], b_o = biap[cq * 4 + 3];
    float cst = 0.f;                 // cell state for (batch bo*8+(ks&7), unit cq)

    // GEMM operand bases (constant across phases)
    const float* const Ab1 = hsA + (bo * 8) * ASTR;          // L1: cols 0:384
    const float* const Wb1 = wT1 + (cq * 4) * W1STR;
    const float* const Ab2 = hsA + (bo * 8) * ASTR + 128;    // L2: cols 128:640
    const float* const Wb2 = wT2 + (cq * 4) * W2STR;

    // publish base for this thread's (unit, batch-oct); +ks per store
    float* const pub1 = h1b + (size_t)(ug * 4 + cq) * NB + bg * 32 + bo * 8;
    float* const pub2 = h2b + (size_t)(ug * 4 + cq) * NB + bg * 32 + bo * 8;

    for (int p = 0; p <= T_SEQ; ++p) {
        // ---- per-wave poll: all 64 lanes read the group's 64 flags ----
        // (p==0 exits immediately: flags start at 0)
        for (;;) {
            int a = ld_flag(grpF + lane);
            if (__all(a >= p)) break;
            __builtin_amdgcn_s_sleep(2);
        }

        // ---- per-wave stage of OWN 8 batch rows + full GEMM + publish ----
        if (half == 0) {
            if (p < T_SEQ) {
                // x rows bo*8..+8, cols 0:128 (cached loads, L2-resident)
                #pragma unroll
                for (int it = 0; it < 4; ++it) {
                    const int idx = lane + it * 64;          // 0..255
                    const int r8 = idx >> 5, c4 = idx & 31;
                    const int row = bo * 8 + r8;
                    v4f v = *(const v4f*)(x + ((size_t)(bg * 32 + row) * T_SEQ + p) * DIN + c4 * 4);
                    *(v4f*)(hsA + row * ASTR + c4 * 4) = v;
                }
                // h1[p-1] cols 128:384, own 4 batch-pairs (CP loads)
                const u64t* hp1 = (const u64t*)(h1b + (size_t)((p + 1) & 1) * SLOT + bg * 32);
                #pragma unroll
                for (int it = 0; it < 16; ++it) {
                    const int idx = lane + it * 64;          // 0..1023
                    const int k = idx >> 2, bb = bo * 4 + (idx & 3);
                    F2U v; v.u = (p == 0) ? 0ull : ld_cp8(hp1 + (size_t)k * 64 + bb);
                    hsA[(bb * 2 + 0) * ASTR + 128 + k] = v.f[0];
                    hsA[(bb * 2 + 1) * ASTR + 128 + k] = v.f[1];
                }
                asm volatile("s_waitcnt lgkmcnt(0)" ::: "memory");
                __builtin_amdgcn_sched_barrier(0);

                float acc[8][4] = {};
                gemm_tile<6, W1STR>(acc, Ab1, Wb1, ks);
                reduce_ew_publish(acc, ks, b_i, b_f, b_g, b_o, cst,
                                  pub1 + (size_t)(p & 1) * SLOT);
            }
        } else {
            if (p >= 1) {
                // h1[p-1] cols 128:384 (duplicate of L1-wave's stage — same
                // source, identical values: benign LDS race)
                const u64t* hp1 = (const u64t*)(h1b + (size_t)((p + 1) & 1) * SLOT + bg * 32);
                #pragma unroll
                for (int it = 0; it < 16; ++it) {
                    const int idx = lane + it * 64;
                    const int k = idx >> 2, bb = bo * 4 + (idx & 3);
                    F2U v; v.u = ld_cp8(hp1 + (size_t)k * 64 + bb);   // p>=1
                    hsA[(bb * 2 + 0) * ASTR + 128 + k] = v.f[0];
                    hsA[(bb * 2 + 1) * ASTR + 128 + k] = v.f[1];
                }
                // h2[p-2] cols 384:640 (settled; CP loads)
                const u64t* hp2 = (const u64t*)(h2b + (size_t)(p & 1) * SLOT + bg * 32);
                #pragma unroll
                for (int it = 0; it < 16; ++it) {
                    const int idx = lane + it * 64;
                    const int k = idx >> 2, bb = bo * 4 + (idx & 3);
                    F2U v; v.u = (p <= 1) ? 0ull : ld_cp8(hp2 + (size_t)k * 64 + bb);
                    hsA[(bb * 2 + 0) * ASTR + 384 + k] = v.f[0];
                    hsA[(bb * 2 + 1) * ASTR + 384 + k] = v.f[1];
                }
                asm volatile("s_waitcnt lgkmcnt(0)" ::: "memory");
                __builtin_amdgcn_sched_barrier(0);

                float acc[8][4] = {};
                gemm_tile<8, W2STR>(acc, Ab2, Wb2, ks);
                reduce_ew_publish(acc, ks, b_i, b_f, b_g, b_o, cst,
                                  pub2 + (size_t)((p + 1) & 1) * SLOT);
            }
        }
        __builtin_amdgcn_s_waitcnt(0);   // drain publish stores pre-B4
        __syncthreads();                 // B4: sole barrier — cross-phase
                                         // hsA separation + flag ordering
        if (tid == 0) st_flag(myF, p + 1);
    }
    // final h2 = step 1023 -> slot 1, at ws + 1024 + SLOT
}

// Dense + softmax: one block per batch row. h2 is [H][B]-major.
__global__ __launch_bounds__(256)
void dense_softmax_kernel(const float* __restrict__ h, const float* __restrict__ Wd,
                          const float* __restrict__ bd, float* __restrict__ out)
{
    __shared__ float hsd[HID];
    __shared__ float red[256];
    const int b = blockIdx.x, tid = threadIdx.x;

    hsd[tid] = h[(size_t)tid * NB + b];
    __syncthreads();

    float a0 = 0.f, a1 = 0.f, a2 = 0.f, a3 = 0.f;
    const bool has3 = (tid < DOUT - 768);
    const int c3 = has3 ? (tid + 768) : 0;
    for (int k = 0; k < HID; ++k) {
        const float hk = hsd[k];
        const float* wr = Wd + (size_t)k * DOUT;
        a0 = fmaf(hk, wr[tid],       a0);
        a1 = fmaf(hk, wr[tid + 256], a1);
        a2 = fmaf(hk, wr[tid + 512], a2);
        a3 = fmaf(hk, wr[c3],        a3);
    }
    a0 += bd[tid]; a1 += bd[tid + 256]; a2 += bd[tid + 512];
    if (has3) a3 += bd[tid + 768];

    float m = fmaxf(fmaxf(a0, a1), a2);
    if (has3) m = fmaxf(m, a3);
    red[tid] = m; __syncthreads();
    for (int s = 128; s > 0; s >>= 1) {
        if (tid < s) red[tid] = fmaxf(red[tid], red[tid + s]);
        __syncthreads();
    }
    const float M = red[0];
    __syncthreads();

    float e0 = expf(a0 - M), e1 = expf(a1 - M), e2 = expf(a2 - M);
    float e3 = has3 ? expf(a3 - M) : 0.f;
    red[tid] = e0 + e1 + e2 + e3; __syncthreads();
    for (int s = 128; s > 0; s >>= 1) {
        if (tid < s) red[tid] += red[tid + s];
        __syncthreads();
    }
    const float inv = 1.f / red[0];

    float* o = out + (size_t)b * DOUT;
    o[tid] = e0 * inv;
    o[tid + 256] = e1 * inv;
    o[tid + 512] = e2 * inv;
    if (has3) o[tid + 768] = e3 * inv;
}

extern "C" void kernel_launch(void* const* d_in, const int* in_sizes, int n_in,
                              void* d_out, int out_size, void* d_ws, size_t ws_size,
                              hipStream_t stream)
{
    const float* x  = (const float*)d_in[0];
    const float* W1 = (const float*)d_in[1];
    const float* U1 = (const float*)d_in[2];
    const float* b1 = (const float*)d_in[3];
    const float* W2 = (const float*)d_in[4];
    const float* U2 = (const float*)d_in[5];
    const float* b2 = (const float*)d_in[6];
    const float* Wd = (const float*)d_in[7];
    const float* bd = (const float*)d_in[8];
    float* out = (float*)d_out;
    float* ws  = (float*)d_ws;

    // h1: 2 slots x 32768 floats in d_out (128000 floats), [slot][H][B];
    // fully overwritten by dense_softmax afterwards (which reads only ws).
    float* h1b = out;

    // flag region (ints 0..1023; groups at bg*128) must start at 0
    hipMemsetAsync(ws, 0, 4096, stream);

    hipFuncSetAttribute((const void*)lstm_fused_kernel,
                        hipFuncAttributeMaxDynamicSharedMemorySize, (int)SMEM_BYTES);

    void* args[] = { (void*)&x, (void*)&W1, (void*)&U1, (void*)&b1,
                     (void*)&W2, (void*)&U2, (void*)&b2,
                     (void*)&h1b, (void*)&ws };
    hipError_t err = hipLaunchCooperativeKernel((const void*)lstm_fused_kernel,
                                                dim3(256), dim3(512), args,
                                                (int)SMEM_BYTES, stream);
    if (err != hipSuccess) {
        // a rejected cooperative launch fails SILENTLY without this check.
        // 256 blocks at 1/CU are co-resident by resource constraints, so a
        // plain launch preserves the flag protocol.
        hipLaunchKernelGGL(lstm_fused_kernel, dim3(256), dim3(512),
                           (int)SMEM_BYTES, stream,
                           x, W1, U1, b1, W2, U2, b2, h1b, ws);
    }

    const float* h2final = ws + 1024 + SLOT;   // slot 1 = h2[1023]
    hipLaunchKernelGGL(dense_softmax_kernel, dim3(128), dim3(256), 0, stream,
                       h2final, Wd, bd, out);
}

// Round 10
// 10585.618 us; speedup vs baseline: 2.3802x; 2.3802x over previous
//
#include <hip/hip_runtime.h>
#include <math.h>

static constexpr int T_SEQ = 1024;
static constexpr int DIN = 128;
static constexpr int HID = 256;
static constexpr int DOUT = 1000;
static constexpr int NB = 128;
static constexpr int SLOT = HID * NB;   // 32768 floats per h slot, [H][B]-major

// LDS layout (floats).
static constexpr int W1STR = 388;              // K=384 + 4
static constexpr int W2STR = 516;              // K=512 + 4
static constexpr int ASTR  = 652;              // [x 0:128 | h1 128:384 | h2 384:640] + 12
static constexpr int OFF_W2 = 16 * W1STR;            // 6208
static constexpr int OFF_A  = OFF_W2 + 16 * W2STR;   // 14464
static constexpr int OFF_B1 = OFF_A + 32 * ASTR;     // 35328
static constexpr int OFF_B2 = OFF_B1 + 16;           // 35344
static constexpr size_t SMEM_BYTES = (size_t)(OFF_B2 + 16) * 4;   // 141,440 B (1 block/CU)

typedef float v4f __attribute__((ext_vector_type(4)));
typedef unsigned long long u64t;

#define SCOPE_AGENT __HIP_MEMORY_SCOPE_AGENT

__device__ __forceinline__ int ld_flag(const int* p) {
    return __hip_atomic_load(p, __ATOMIC_RELAXED, SCOPE_AGENT);
}
__device__ __forceinline__ void st_flag(int* p, int v) {
    __hip_atomic_store(p, v, __ATOMIC_RELAXED, SCOPE_AGENT);
}
// write-through 8B store to the coherence point. R17: publishes packed in
// pairs (R16-proven correctness) — halves CP store REQUESTS (rate-limited
// resource per the R17 theory), same bytes.
__device__ __forceinline__ void st_cp8(u64t* p, u64t v) {
    __hip_atomic_store(p, v, __ATOMIC_RELAXED, SCOPE_AGENT);
}
// R17: 16B coherence-point load (sc0 sc1 = same cache-bypass semantics the
// compiler emits for __hip_atomic_load, at dwordx4 width). Halves h-staging
// request count vs the R13 8B loads. Issued in batches; consumer must
// execute s_waitcnt vmcnt(0) (volatile asm) before reading the output regs.
__device__ __forceinline__ void ld_cp16(v4f* dst, const float* src) {
    asm volatile("global_load_dwordx4 %0, %1, off sc0 sc1"
                 : "=v"(*dst) : "v"(src));
}

union F2U { u64t u; float f[2]; };

__device__ __forceinline__ float dot4(float acc, v4f va, v4f vb) {
    return fmaf(va.x, vb.x, fmaf(va.y, vb.y,
           fmaf(va.z, vb.z, fmaf(va.w, vb.w, acc))));
}

// R13 GEMM tile (proven best): 8 batches x 4 cols per thread, k-split 16
// within the wave; lane = ks(bits0-3) | cq(bits4-5); wave-in-half = bo.
// k chunks interleaved (j*16+ks)*4: each 16-lane ks group reads a
// contiguous 256B run; the 4 cq groups broadcast the same A addresses.
template<int NCHUNK, int WSTR>
__device__ __forceinline__ void gemm_tile(float acc[8][4],
                                          const float* __restrict__ Ab,
                                          const float* __restrict__ Wb,
                                          const int ks)
{
    #pragma unroll
    for (int j = 0; j < NCHUNK; ++j) {
        const int ko = (j * 16 + ks) * 4;
        v4f a[8], w[4];
        #pragma unroll
        for (int i = 0; i < 8; ++i) a[i] = *(const v4f*)(Ab + i * ASTR + ko);
        #pragma unroll
        for (int c = 0; c < 4; ++c) w[c] = *(const v4f*)(Wb + c * WSTR + ko);
        #pragma unroll
        for (int i = 0; i < 8; ++i)
            #pragma unroll
            for (int c = 0; c < 4; ++c)
                acc[i][c] = dot4(acc[i][c], a[i], w[c]);
    }
}

// Fold-reduce acc over the 16 ks lanes with ownership halving
// (xor4 -> xor2 -> xor1 -> xor8). Lane ks ends owning the COMPLETE z
// (4 gates) for batch bo*8+(ks&7), unit cq; ew + state update in
// registers. Publish PACKED: even ks<8 lanes store {hv, hv@ks+1} as one
// 8B CP store (R16-proven). All indices compile-time (rule 20).
__device__ __forceinline__ void reduce_ew_publish(float acc[8][4], const int ks,
    const float b_i, const float b_f, const float b_g, const float b_o,
    float& cst, float* __restrict__ hb)
{
    #pragma unroll
    for (int i = 0; i < 8; ++i)
        #pragma unroll
        for (int c = 0; c < 4; ++c)
            acc[i][c] += __shfl_xor(acc[i][c], 4);
    float s1[4][4];
    const bool kb2 = (ks & 4) != 0;
    #pragma unroll
    for (int i = 0; i < 4; ++i)
        #pragma unroll
        for (int c = 0; c < 4; ++c)
            s1[i][c] = kb2 ? acc[i + 4][c] : acc[i][c];
    #pragma unroll
    for (int i = 0; i < 4; ++i)
        #pragma unroll
        for (int c = 0; c < 4; ++c)
            s1[i][c] += __shfl_xor(s1[i][c], 2);
    float s2[2][4];
    const bool kb1 = (ks & 2) != 0;
    #pragma unroll
    for (int i = 0; i < 2; ++i)
        #pragma unroll
        for (int c = 0; c < 4; ++c)
            s2[i][c] = kb1 ? s1[i + 2][c] : s1[i][c];
    #pragma unroll
    for (int i = 0; i < 2; ++i)
        #pragma unroll
        for (int c = 0; c < 4; ++c)
            s2[i][c] += __shfl_xor(s2[i][c], 1);
    float z4[4];
    const bool kb0 = (ks & 1) != 0;
    #pragma unroll
    for (int c = 0; c < 4; ++c)
        z4[c] = kb0 ? s2[1][c] : s2[0][c];
    #pragma unroll
    for (int c = 0; c < 4; ++c)
        z4[c] += __shfl_xor(z4[c], 8);

    const float zi = z4[0] + b_i, zf = z4[1] + b_f;
    const float zg = z4[2] + b_g, zo = z4[3] + b_o;
    const float ig = 1.f / (1.f + expf(-zi));
    const float fg = 1.f / (1.f + expf(-zf));
    const float gg = fmaxf(zg, 0.f);
    const float og = 1.f / (1.f + expf(-zo));
    cst = fg * cst + ig * gg;
    const float hv = og * fmaxf(cst, 0.f);
    F2U pk; pk.f[0] = hv; pk.f[1] = __shfl_xor(hv, 1);
    if ((ks & 9) == 0)                       // even ks < 8
        st_cp8((u64t*)(hb + ks), pk.u);      // hb+ks even -> 8B aligned
}

// Fused 2-layer LSTM, 256 blocks x 512 threads, 1 block/CU (LDS 141.4 KB).
// R13 skeleton (proven best, 13.33 ms): lockstep, waves 0-3 = L1 step p,
// waves 4-7 = L2 step p-1; block-cooperative staging (R16 lesson:
// per-wave staging destroys coalescing, FETCH 3.4x); fence-free CP
// protocol; h2 prestaged pre-poll; 3 barriers (B1/B2/B4).
// R17 (single theory: MALL UC request-rate is the wall): staging loads
// 8B->16B (halves requests), publishes 4B->8B (halves requests).
__global__ __launch_bounds__(512)
void lstm_fused_kernel(const float* __restrict__ x,
                       const float* __restrict__ W1, const float* __restrict__ U1,
                       const float* __restrict__ b1,
                       const float* __restrict__ W2, const float* __restrict__ U2,
                       const float* __restrict__ b2,
                       float* __restrict__ h1b,   // 2*SLOT (d_out scratch), [slot][H][B]
                       float* __restrict__ ws)    // [1024 ints: flags][2*SLOT h2 [H][B]]
{
    extern __shared__ float smem[];
    float* wT1  = smem;
    float* wT2  = smem + OFF_W2;
    float* hsA  = smem + OFF_A;
    float* bia1 = smem + OFF_B1;
    float* bia2 = smem + OFF_B2;

    int*   F   = (int*)ws;          // 4 groups x 128 ints (first 64 used each)
    float* h2b = ws + 1024;

    const int tid = threadIdx.x;
    const int bid = blockIdx.x;
    const int bg  = bid >> 6;       // batch group 0..3 (batches bg*32..+31)
    const int ug  = bid & 63;       // unit group (units ug*4..+3)
    int* grpF = F + bg * 128;
    int* myF  = grpF + ug;

    const int lane = tid & 63;
    const int ks   = lane & 15;     // in-wave k-split index
    const int cq   = lane >> 4;     // col quad = unit 0..3
    const int half = tid >> 8;      // 0: L1 waves, 1: L2 waves
    const int bo   = (tid >> 6) & 3;// wave-in-half = batch oct

    // staging cell mapping (block-cooperative, 16B grain):
    // idx = tid + it*512 in [0,2048): k = idx>>3 (0..255), q = idx&7.
    // load 16B = batches q*4..q*4+3 of k-row; write 4 LDS rows.
    const int sk = tid >> 3;        // base k for it=0 (advances by 64/it)
    const int sq = tid & 7;

    // ---- one-time: both weight tiles (transposed) + biases into LDS ----
    {
        const int hf = tid >> 8;
        const int t  = tid & 255;
        const int K    = hf ? 512 : 384;
        const int len0 = hf ? 256 : 128;
        const float* Wp = hf ? W2 : W1;
        const float* Up = hf ? U2 : U1;
        float* wt = hf ? wT2 : wT1;
        const int wstr = hf ? W2STR : W1STR;
        for (int c = 0; c < 16; ++c) {
            const int col = (c & 3) * HID + ug * 4 + (c >> 2);   // gate-major
            for (int k = t; k < K; k += 256)
                wt[c * wstr + k] = (k < len0) ? Wp[(size_t)k * (4 * HID) + col]
                                              : Up[(size_t)(k - len0) * (4 * HID) + col];
        }
    }
    if (tid < 16)                     bia1[tid] = b1[(tid & 3) * HID + ug * 4 + (tid >> 2)];
    else if (tid >= 256 && tid < 272) { const int t = tid - 256;
                                        bia2[t]  = b2[(t & 3) * HID + ug * 4 + (t >> 2)]; }
    __syncthreads();

    // per-thread persistent state: bias regs (constant all phases) + cell st
    const float* biap = half ? bia2 : bia1;
    const float b_i = biap[cq * 4 + 0], b_f = biap[cq * 4 + 1];
    const float b_g = biap[cq * 4 + 2], b_o = biap[cq * 4 + 3];
    float cst = 0.f;                 // cell state for (batch bo*8+(ks&7), unit cq)

    // GEMM operand bases (constant across phases)
    const float* const Ab1 = hsA + (bo * 8) * ASTR;          // L1: cols 0:384
    const float* const Wb1 = wT1 + (cq * 4) * W1STR;
    const float* const Ab2 = hsA + (bo * 8) * ASTR + 128;    // L2: cols 128:640
    const float* const Wb2 = wT2 + (cq * 4) * W2STR;

    // publish base for this thread's (unit, batch-oct); +ks per store
    float* const pub1 = h1b + (size_t)(ug * 4 + cq) * NB + bg * 32 + bo * 8;
    float* const pub2 = h2b + (size_t)(ug * 4 + cq) * NB + bg * 32 + bo * 8;

    const v4f vzero = {0.f, 0.f, 0.f, 0.f};

    for (int p = 0; p <= T_SEQ; ++p) {
        // ---- PRE-POLL: x_p prestage (cached, L2-resident) ----
        if (p < T_SEQ) {
            #pragma unroll
            for (int it = 0; it < 2; ++it) {
                const int idx = tid + it * 512, r = idx >> 5, c4 = idx & 31;
                v4f v = *(const v4f*)(x + ((size_t)(bg * 32 + r) * T_SEQ + p) * DIN + c4 * 4);
                *(v4f*)(hsA + r * ASTR + c4 * 4) = v;
            }
        }
        // ---- PRE-POLL: h2[p-2] stage (settled at phase p-1's poll).
        //      16B UC loads, batched issue -> vmcnt(0) -> LDS writes. ----
        {
            const float* hp2 = h2b + (size_t)(p & 1) * SLOT + bg * 32;
            v4f hv[4];
            if (p <= 1) {
                #pragma unroll
                for (int it = 0; it < 4; ++it) hv[it] = vzero;
            } else {
                #pragma unroll
                for (int it = 0; it < 4; ++it) {
                    const int k = sk + it * 64;
                    ld_cp16(&hv[it], hp2 + (size_t)k * NB + sq * 4);
                }
                asm volatile("s_waitcnt vmcnt(0)" ::: "memory");
                __builtin_amdgcn_sched_barrier(0);
            }
            #pragma unroll
            for (int it = 0; it < 4; ++it) {
                const int k = sk + it * 64;
                hsA[(sq * 4 + 0) * ASTR + 384 + k] = hv[it].x;
                hsA[(sq * 4 + 1) * ASTR + 384 + k] = hv[it].y;
                hsA[(sq * 4 + 2) * ASTR + 384 + k] = hv[it].z;
                hsA[(sq * 4 + 3) * ASTR + 384 + k] = hv[it].w;
            }
        }
        // wave0: all 64 group blocks finished phase p-1. NO fence (R13).
        if (tid < 64) {
            for (;;) {
                int a = ld_flag(grpF + tid);
                if (__all(a >= p)) break;
                __builtin_amdgcn_s_sleep(1);
            }
        }
        __syncthreads();                                    // B1

        // ---- h1[p-1] stage -> cols 128:384. 16B UC loads. ----
        {
            const float* hp1 = h1b + (size_t)((p + 1) & 1) * SLOT + bg * 32;
            v4f hv[4];
            if (p == 0) {
                #pragma unroll
                for (int it = 0; it < 4; ++it) hv[it] = vzero;
            } else {
                #pragma unroll
                for (int it = 0; it < 4; ++it) {
                    const int k = sk + it * 64;
                    ld_cp16(&hv[it], hp1 + (size_t)k * NB + sq * 4);
                }
                asm volatile("s_waitcnt vmcnt(0)" ::: "memory");
                __builtin_amdgcn_sched_barrier(0);
            }
            #pragma unroll
            for (int it = 0; it < 4; ++it) {
                const int k = sk + it * 64;
                hsA[(sq * 4 + 0) * ASTR + 128 + k] = hv[it].x;
                hsA[(sq * 4 + 1) * ASTR + 128 + k] = hv[it].y;
                hsA[(sq * 4 + 2) * ASTR + 128 + k] = hv[it].z;
                hsA[(sq * 4 + 3) * ASTR + 128 + k] = hv[it].w;
            }
        }
        __syncthreads();                                    // B2

        // ---- GEMM + in-register reduce/ew/publish per half ----
        if (half == 0) {
            if (p < T_SEQ) {
                float acc[8][4] = {};
                gemm_tile<6, W1STR>(acc, Ab1, Wb1, ks);
                reduce_ew_publish(acc, ks, b_i, b_f, b_g, b_o, cst,
                                  pub1 + (size_t)(p & 1) * SLOT);
            }
        } else {
            if (p >= 1) {
                float acc[8][4] = {};
                gemm_tile<8, W2STR>(acc, Ab2, Wb2, ks);
                reduce_ew_publish(acc, ks, b_i, b_f, b_g, b_o, cst,
                                  pub2 + (size_t)((p + 1) & 1) * SLOT);
            }
        }
        __builtin_amdgcn_s_waitcnt(0);   // drain publish stores pre-B4
        __syncthreads();                                    // B4
        if (tid == 0) st_flag(myF, p + 1);
    }
    // final h2 = step 1023 -> slot 1, at ws + 1024 + SLOT
}

// Dense + softmax: one block per batch row. h2 is [H][B]-major.
__global__ __launch_bounds__(256)
void dense_softmax_kernel(const float* __restrict__ h, const float* __restrict__ Wd,
                          const float* __restrict__ bd, float* __restrict__ out)
{
    __shared__ float hsd[HID];
    __shared__ float red[256];
    const int b = blockIdx.x, tid = threadIdx.x;

    hsd[tid] = h[(size_t)tid * NB + b];
    __syncthreads();

    float a0 = 0.f, a1 = 0.f, a2 = 0.f, a3 = 0.f;
    const bool has3 = (tid < DOUT - 768);
    const int c3 = has3 ? (tid + 768) : 0;
    for (int k = 0; k < HID; ++k) {
        const float hk = hsd[k];
        const float* wr = Wd + (size_t)k * DOUT;
        a0 = fmaf(hk, wr[tid],       a0);
        a1 = fmaf(hk, wr[tid + 256], a1);
        a2 = fmaf(hk, wr[tid + 512], a2);
        a3 = fmaf(hk, wr[c3],        a3);
    }
    a0 += bd[tid]; a1 += bd[tid + 256]; a2 += bd[tid + 512];
    if (has3) a3 += bd[tid + 768];

    float m = fmaxf(fmaxf(a0, a1), a2);
    if (has3) m = fmaxf(m, a3);
    red[tid] = m; __syncthreads();
    for (int s = 128; s > 0; s >>= 1) {
        if (tid < s) red[tid] = fmaxf(red[tid], red[tid + s]);
        __syncthreads();
    }
    const float M = red[0];
    __syncthreads();

    float e0 = expf(a0 - M), e1 = expf(a1 - M), e2 = expf(a2 - M);
    float e3 = has3 ? expf(a3 - M) : 0.f;
    red[tid] = e0 + e1 + e2 + e3; __syncthreads();
    for (int s = 128; s > 0; s >>= 1) {
        if (tid < s) red[tid] += red[tid + s];
        __syncthreads();
    }
    const float inv = 1.f / red[0];

    float* o = out + (size_t)b * DOUT;
    o[tid] = e0 * inv;
    o[tid + 256] = e1 * inv;
    o[tid + 512] = e2 * inv;
    if (has3) o[tid + 768] = e3 * inv;
}

extern "C" void kernel_launch(void* const* d_in, const int* in_sizes, int n_in,
                              void* d_out, int out_size, void* d_ws, size_t ws_size,
                              hipStream_t stream)
{
    const float* x  = (const float*)d_in[0];
    const float* W1 = (const float*)d_in[1];
    const float* U1 = (const float*)d_in[2];
    const float* b1 = (const float*)d_in[3];
    const float* W2 = (const float*)d_in[4];
    const float* U2 = (const float*)d_in[5];
    const float* b2 = (const float*)d_in[6];
    const float* Wd = (const float*)d_in[7];
    const float* bd = (const float*)d_in[8];
    float* out = (float*)d_out;
    float* ws  = (float*)d_ws;

    // h1: 2 slots x 32768 floats in d_out (128000 floats), [slot][H][B];
    // fully overwritten by dense_softmax afterwards (which reads only ws).
    float* h1b = out;

    // flag region (ints 0..1023; groups at bg*128) must start at 0
    hipMemsetAsync(ws, 0, 4096, stream);

    hipFuncSetAttribute((const void*)lstm_fused_kernel,
                        hipFuncAttributeMaxDynamicSharedMemorySize, (int)SMEM_BYTES);

    void* args[] = { (void*)&x, (void*)&W1, (void*)&U1, (void*)&b1,
                     (void*)&W2, (void*)&U2, (void*)&b2,
                     (void*)&h1b, (void*)&ws };
    hipError_t err = hipLaunchCooperativeKernel((const void*)lstm_fused_kernel,
                                                dim3(256), dim3(512), args,
                                                (int)SMEM_BYTES, stream);
    if (err != hipSuccess) {
        // a rejected cooperative launch fails SILENTLY without this check.
        // 256 blocks at 1/CU are co-resident by resource constraints, so a
        // plain launch preserves the flag protocol.
        hipLaunchKernelGGL(lstm_fused_kernel, dim3(256), dim3(512),
                           (int)SMEM_BYTES, stream,
                           x, W1, U1, b1, W2, U2, b2, h1b, ws);
    }

    const float* h2final = ws + 1024 + SLOT;   // slot 1 = h2[1023]
    hipLaunchKernelGGL(dense_softmax_kernel, dim3(128), dim3(256), 0, stream,
                       h2final, Wd, bd, out);
}

// Round 11
// 6898.795 us; speedup vs baseline: 3.6521x; 1.5344x over previous
//
#include <hip/hip_runtime.h>
#include <math.h>

static constexpr int T_SEQ = 1024;
static constexpr int DIN = 128;
static constexpr int HID = 256;
static constexpr int DOUT = 1000;
static constexpr int NB = 128;
static constexpr int SLOT = HID * NB;   // 32768 floats per h slot, [H][B]-major

// LDS layout (floats).
static constexpr int W1STR = 388;              // K=384 + 4
static constexpr int W2STR = 516;              // K=512 + 4
static constexpr int ASTR  = 652;              // [x 0:128 | h1 128:384 | h2 384:640] + 12
static constexpr int OFF_W2 = 16 * W1STR;            // 6208
static constexpr int OFF_A  = OFF_W2 + 16 * W2STR;   // 14464
static constexpr int OFF_B1 = OFF_A + 32 * ASTR;     // 35328
static constexpr int OFF_B2 = OFF_B1 + 16;           // 35344
static constexpr size_t SMEM_BYTES = (size_t)(OFF_B2 + 16) * 4;   // 141,440 B (1 block/CU)

typedef float v4f __attribute__((ext_vector_type(4)));
typedef unsigned long long u64t;

#define SCOPE_AGENT __HIP_MEMORY_SCOPE_AGENT

__device__ __forceinline__ int ld_flag(const int* p) {
    return __hip_atomic_load(p, __ATOMIC_RELAXED, SCOPE_AGENT);
}
__device__ __forceinline__ void st_flag(int* p, int v) {
    __hip_atomic_store(p, v, __ATOMIC_RELAXED, SCOPE_AGENT);
}
// write-through 8B store to the coherence point (R17: packed publish pairs
// — halves CP store requests).
__device__ __forceinline__ void st_cp8(u64t* p, u64t v) {
    __hip_atomic_store(p, v, __ATOMIC_RELAXED, SCOPE_AGENT);
}
// R17 (proven, -21%): 16B coherence-point load (sc0 sc1 cache-bypass).
// Batched issue; consumer executes s_waitcnt vmcnt(0) before reading regs.
__device__ __forceinline__ void ld_cp16(v4f* dst, const float* src) {
    asm volatile("global_load_dwordx4 %0, %1, off sc0 sc1"
                 : "=v"(*dst) : "v"(src));
}

union F2U { u64t u; float f[2]; };

__device__ __forceinline__ float dot4(float acc, v4f va, v4f vb) {
    return fmaf(va.x, vb.x, fmaf(va.y, vb.y,
           fmaf(va.z, vb.z, fmaf(va.w, vb.w, acc))));
}

// R13/R17 GEMM tile (proven): 8 batches x 4 cols per thread, k-split 16
// within the wave; lane = ks(bits0-3) | cq(bits4-5); wave-in-half = bo.
template<int NCHUNK, int WSTR>
__device__ __forceinline__ void gemm_tile(float acc[8][4],
                                          const float* __restrict__ Ab,
                                          const float* __restrict__ Wb,
                                          const int ks)
{
    #pragma unroll
    for (int j = 0; j < NCHUNK; ++j) {
        const int ko = (j * 16 + ks) * 4;
        v4f a[8], w[4];
        #pragma unroll
        for (int i = 0; i < 8; ++i) a[i] = *(const v4f*)(Ab + i * ASTR + ko);
        #pragma unroll
        for (int c = 0; c < 4; ++c) w[c] = *(const v4f*)(Wb + c * WSTR + ko);
        #pragma unroll
        for (int i = 0; i < 8; ++i)
            #pragma unroll
            for (int c = 0; c < 4; ++c)
                acc[i][c] = dot4(acc[i][c], a[i], w[c]);
    }
}

// R18: IN-PLACE fold-reduce (xor4 -> halve -> xor2 -> halve -> xor1 ->
// halve -> xor8), overwriting acc itself with predicated selects.
// Rationale: R10's s1[4][4]/s2[2][4]/z4[4] temp arrays + cross-array ?:
// selects are the prime suspect for the 31 GB/dispatch scratch-writeback
// (WRITE_SIZE was 0.27 GB through R9, 31 GB from R10 on, invariant under
// every protocol change R11-R17 — only the fold is unique to R10+).
// In-place halving frees acc[4..7] immediately and eliminates ~28
// temporaries; math is IDENTICAL (wave64 lockstep keeps shuffle partners
// consistent: partners of xor2/xor1/xor8 share the same kb2/kb1/kb0).
// Lane ks ends owning the COMPLETE z (4 gates) for batch bo*8+(ks&7),
// unit cq, in acc[0][0..3]. Publish packed 8B (R16/R17-proven).
__device__ __forceinline__ void reduce_ew_publish(float acc[8][4], const int ks,
    const float b_i, const float b_f, const float b_g, const float b_o,
    float& cst, float* __restrict__ hb)
{
    #pragma unroll
    for (int i = 0; i < 8; ++i)
        #pragma unroll
        for (int c = 0; c < 4; ++c)
            acc[i][c] += __shfl_xor(acc[i][c], 4);
    const bool kb2 = (ks & 4) != 0;
    #pragma unroll
    for (int i = 0; i < 4; ++i)
        #pragma unroll
        for (int c = 0; c < 4; ++c) {
            acc[i][c] = kb2 ? acc[i + 4][c] : acc[i][c];
            acc[i][c] += __shfl_xor(acc[i][c], 2);
        }
    const bool kb1 = (ks & 2) != 0;
    #pragma unroll
    for (int i = 0; i < 2; ++i)
        #pragma unroll
        for (int c = 0; c < 4; ++c) {
            acc[i][c] = kb1 ? acc[i + 2][c] : acc[i][c];
            acc[i][c] += __shfl_xor(acc[i][c], 1);
        }
    const bool kb0 = (ks & 1) != 0;
    #pragma unroll
    for (int c = 0; c < 4; ++c) {
        acc[0][c] = kb0 ? acc[1][c] : acc[0][c];
        acc[0][c] += __shfl_xor(acc[0][c], 8);
    }

    const float zi = acc[0][0] + b_i, zf = acc[0][1] + b_f;
    const float zg = acc[0][2] + b_g, zo = acc[0][3] + b_o;
    const float ig = 1.f / (1.f + expf(-zi));
    const float fg = 1.f / (1.f + expf(-zf));
    const float gg = fmaxf(zg, 0.f);
    const float og = 1.f / (1.f + expf(-zo));
    cst = fg * cst + ig * gg;
    const float hv = og * fmaxf(cst, 0.f);
    F2U pk; pk.f[0] = hv; pk.f[1] = __shfl_xor(hv, 1);
    if ((ks & 9) == 0)                       // even ks < 8
        st_cp8((u64t*)(hb + ks), pk.u);      // hb+ks even -> 8B aligned
}

// Fused 2-layer LSTM, 256 blocks x 512 threads, 1 block/CU (LDS 141.4 KB).
// R17 skeleton (proven best, 10.59 ms): lockstep, waves 0-3 = L1 step p,
// waves 4-7 = L2 step p-1; block-cooperative staging with 16B UC loads;
// fence-free CP protocol; h2 prestaged pre-poll; packed 8B publishes;
// 3 barriers (B1/B2/B4). R18 changes ONLY the fold (see above).
__global__ __launch_bounds__(512)
void lstm_fused_kernel(const float* __restrict__ x,
                       const float* __restrict__ W1, const float* __restrict__ U1,
                       const float* __restrict__ b1,
                       const float* __restrict__ W2, const float* __restrict__ U2,
                       const float* __restrict__ b2,
                       float* __restrict__ h1b,   // 2*SLOT (d_out scratch), [slot][H][B]
                       float* __restrict__ ws)    // [1024 ints: flags][2*SLOT h2 [H][B]]
{
    extern __shared__ float smem[];
    float* wT1  = smem;
    float* wT2  = smem + OFF_W2;
    float* hsA  = smem + OFF_A;
    float* bia1 = smem + OFF_B1;
    float* bia2 = smem + OFF_B2;

    int*   F   = (int*)ws;          // 4 groups x 128 ints (first 64 used each)
    float* h2b = ws + 1024;

    const int tid = threadIdx.x;
    const int bid = blockIdx.x;
    const int bg  = bid >> 6;       // batch group 0..3 (batches bg*32..+31)
    const int ug  = bid & 63;       // unit group (units ug*4..+3)
    int* grpF = F + bg * 128;
    int* myF  = grpF + ug;

    const int lane = tid & 63;
    const int ks   = lane & 15;     // in-wave k-split index
    const int cq   = lane >> 4;     // col quad = unit 0..3
    const int half = tid >> 8;      // 0: L1 waves, 1: L2 waves
    const int bo   = (tid >> 6) & 3;// wave-in-half = batch oct

    // staging cell mapping (block-cooperative, 16B grain):
    // idx = tid + it*512 in [0,2048): k = idx>>3, q = idx&7.
    const int sk = tid >> 3;        // base k for it=0 (advances by 64/it)
    const int sq = tid & 7;

    // ---- one-time: both weight tiles (transposed) + biases into LDS ----
    {
        const int hf = tid >> 8;
        const int t  = tid & 255;
        const int K    = hf ? 512 : 384;
        const int len0 = hf ? 256 : 128;
        const float* Wp = hf ? W2 : W1;
        const float* Up = hf ? U2 : U1;
        float* wt = hf ? wT2 : wT1;
        const int wstr = hf ? W2STR : W1STR;
        for (int c = 0; c < 16; ++c) {
            const int col = (c & 3) * HID + ug * 4 + (c >> 2);   // gate-major
            for (int k = t; k < K; k += 256)
                wt[c * wstr + k] = (k < len0) ? Wp[(size_t)k * (4 * HID) + col]
                                              : Up[(size_t)(k - len0) * (4 * HID) + col];
        }
    }
    if (tid < 16)                     bia1[tid] = b1[(tid & 3) * HID + ug * 4 + (tid >> 2)];
    else if (tid >= 256 && tid < 272) { const int t = tid - 256;
                                        bia2[t]  = b2[(t & 3) * HID + ug * 4 + (t >> 2)]; }
    __syncthreads();

    // per-thread persistent state: bias regs (constant all phases) + cell st
    const float* biap = half ? bia2 : bia1;
    const float b_i = biap[cq * 4 + 0], b_f = biap[cq * 4 + 1];
    const float b_g = biap[cq * 4 + 2], b_o = biap[cq * 4 + 3];
    float cst = 0.f;                 // cell state for (batch bo*8+(ks&7), unit cq)

    // GEMM operand bases (constant across phases)
    const float* const Ab1 = hsA + (bo * 8) * ASTR;          // L1: cols 0:384
    const float* const Wb1 = wT1 + (cq * 4) * W1STR;
    const float* const Ab2 = hsA + (bo * 8) * ASTR + 128;    // L2: cols 128:640
    const float* const Wb2 = wT2 + (cq * 4) * W2STR;

    // publish base for this thread's (unit, batch-oct); +ks per store
    float* const pub1 = h1b + (size_t)(ug * 4 + cq) * NB + bg * 32 + bo * 8;
    float* const pub2 = h2b + (size_t)(ug * 4 + cq) * NB + bg * 32 + bo * 8;

    const v4f vzero = {0.f, 0.f, 0.f, 0.f};

    for (int p = 0; p <= T_SEQ; ++p) {
        // ---- PRE-POLL: x_p prestage (cached, L2-resident) ----
        if (p < T_SEQ) {
            #pragma unroll
            for (int it = 0; it < 2; ++it) {
                const int idx = tid + it * 512, r = idx >> 5, c4 = idx & 31;
                v4f v = *(const v4f*)(x + ((size_t)(bg * 32 + r) * T_SEQ + p) * DIN + c4 * 4);
                *(v4f*)(hsA + r * ASTR + c4 * 4) = v;
            }
        }
        // ---- PRE-POLL: h2[p-2] stage (settled at phase p-1's poll).
        //      16B UC loads, batched issue -> vmcnt(0) -> LDS writes. ----
        {
            const float* hp2 = h2b + (size_t)(p & 1) * SLOT + bg * 32;
            v4f hv[4];
            if (p <= 1) {
                #pragma unroll
                for (int it = 0; it < 4; ++it) hv[it] = vzero;
            } else {
                #pragma unroll
                for (int it = 0; it < 4; ++it) {
                    const int k = sk + it * 64;
                    ld_cp16(&hv[it], hp2 + (size_t)k * NB + sq * 4);
                }
                asm volatile("s_waitcnt vmcnt(0)" ::: "memory");
                __builtin_amdgcn_sched_barrier(0);
            }
            #pragma unroll
            for (int it = 0; it < 4; ++it) {
                const int k = sk + it * 64;
                hsA[(sq * 4 + 0) * ASTR + 384 + k] = hv[it].x;
                hsA[(sq * 4 + 1) * ASTR + 384 + k] = hv[it].y;
                hsA[(sq * 4 + 2) * ASTR + 384 + k] = hv[it].z;
                hsA[(sq * 4 + 3) * ASTR + 384 + k] = hv[it].w;
            }
        }
        // wave0: all 64 group blocks finished phase p-1. NO fence (R13).
        if (tid < 64) {
            for (;;) {
                int a = ld_flag(grpF + tid);
                if (__all(a >= p)) break;
                __builtin_amdgcn_s_sleep(1);
            }
        }
        __syncthreads();                                    // B1

        // ---- h1[p-1] stage -> cols 128:384. 16B UC loads. ----
        {
            const float* hp1 = h1b + (size_t)((p + 1) & 1) * SLOT + bg * 32;
            v4f hv[4];
            if (p == 0) {
                #pragma unroll
                for (int it = 0; it < 4; ++it) hv[it] = vzero;
            } else {
                #pragma unroll
                for (int it = 0; it < 4; ++it) {
                    const int k = sk + it * 64;
                    ld_cp16(&hv[it], hp1 + (size_t)k * NB + sq * 4);
                }
                asm volatile("s_waitcnt vmcnt(0)" ::: "memory");
                __builtin_amdgcn_sched_barrier(0);
            }
            #pragma unroll
            for (int it = 0; it < 4; ++it) {
                const int k = sk + it * 64;
                hsA[(sq * 4 + 0) * ASTR + 128 + k] = hv[it].x;
                hsA[(sq * 4 + 1) * ASTR + 128 + k] = hv[it].y;
                hsA[(sq * 4 + 2) * ASTR + 128 + k] = hv[it].z;
                hsA[(sq * 4 + 3) * ASTR + 128 + k] = hv[it].w;
            }
        }
        __syncthreads();                                    // B2

        // ---- GEMM + in-register reduce/ew/publish per half ----
        if (half == 0) {
            if (p < T_SEQ) {
                float acc[8][4] = {};
                gemm_tile<6, W1STR>(acc, Ab1, Wb1, ks);
                reduce_ew_publish(acc, ks, b_i, b_f, b_g, b_o, cst,
                                  pub1 + (size_t)(p & 1) * SLOT);
            }
        } else {
            if (p >= 1) {
                float acc[8][4] = {};
                gemm_tile<8, W2STR>(acc, Ab2, Wb2, ks);
                reduce_ew_publish(acc, ks, b_i, b_f, b_g, b_o, cst,
                                  pub2 + (size_t)((p + 1) & 1) * SLOT);
            }
        }
        __builtin_amdgcn_s_waitcnt(0);   // drain publish stores pre-B4
        __syncthreads();                                    // B4
        if (tid == 0) st_flag(myF, p + 1);
    }
    // final h2 = step 1023 -> slot 1, at ws + 1024 + SLOT
}

// Dense + softmax: one block per batch row. h2 is [H][B]-major.
__global__ __launch_bounds__(256)
void dense_softmax_kernel(const float* __restrict__ h, const float* __restrict__ Wd,
                          const float* __restrict__ bd, float* __restrict__ out)
{
    __shared__ float hsd[HID];
    __shared__ float red[256];
    const int b = blockIdx.x, tid = threadIdx.x;

    hsd[tid] = h[(size_t)tid * NB + b];
    __syncthreads();

    float a0 = 0.f, a1 = 0.f, a2 = 0.f, a3 = 0.f;
    const bool has3 = (tid < DOUT - 768);
    const int c3 = has3 ? (tid + 768) : 0;
    for (int k = 0; k < HID; ++k) {
        const float hk = hsd[k];
        const float* wr = Wd + (size_t)k * DOUT;
        a0 = fmaf(hk, wr[tid],       a0);
        a1 = fmaf(hk, wr[tid + 256], a1);
        a2 = fmaf(hk, wr[tid + 512], a2);
        a3 = fmaf(hk, wr[c3],        a3);
    }
    a0 += bd[tid]; a1 += bd[tid + 256]; a2 += bd[tid + 512];
    if (has3) a3 += bd[tid + 768];

    float m = fmaxf(fmaxf(a0, a1), a2);
    if (has3) m = fmaxf(m, a3);
    red[tid] = m; __syncthreads();
    for (int s = 128; s > 0; s >>= 1) {
        if (tid < s) red[tid] = fmaxf(red[tid], red[tid + s]);
        __syncthreads();
    }
    const float M = red[0];
    __syncthreads();

    float e0 = expf(a0 - M), e1 = expf(a1 - M), e2 = expf(a2 - M);
    float e3 = has3 ? expf(a3 - M) : 0.f;
    red[tid] = e0 + e1 + e2 + e3; __syncthreads();
    for (int s = 128; s > 0; s >>= 1) {
        if (tid < s) red[tid] += red[tid + s];
        __syncthreads();
    }
    const float inv = 1.f / red[0];

    float* o = out + (size_t)b * DOUT;
    o[tid] = e0 * inv;
    o[tid + 256] = e1 * inv;
    o[tid + 512] = e2 * inv;
    if (has3) o[tid + 768] = e3 * inv;
}

extern "C" void kernel_launch(void* const* d_in, const int* in_sizes, int n_in,
                              void* d_out, int out_size, void* d_ws, size_t ws_size,
                              hipStream_t stream)
{
    const float* x  = (const float*)d_in[0];
    const float* W1 = (const float*)d_in[1];
    const float* U1 = (const float*)d_in[2];
    const float* b1 = (const float*)d_in[3];
    const float* W2 = (const float*)d_in[4];
    const float* U2 = (const float*)d_in[5];
    const float* b2 = (const float*)d_in[6];
    const float* Wd = (const float*)d_in[7];
    const float* bd = (const float*)d_in[8];
    float* out = (float*)d_out;
    float* ws  = (float*)d_ws;

    // h1: 2 slots x 32768 floats in d_out (128000 floats), [slot][H][B];
    // fully overwritten by dense_softmax afterwards (which reads only ws).
    float* h1b = out;

    // flag region (ints 0..1023; groups at bg*128) must start at 0
    hipMemsetAsync(ws, 0, 4096, stream);

    hipFuncSetAttribute((const void*)lstm_fused_kernel,
                        hipFuncAttributeMaxDynamicSharedMemorySize, (int)SMEM_BYTES);

    void* args[] = { (void*)&x, (void*)&W1, (void*)&U1, (void*)&b1,
                     (void*)&W2, (void*)&U2, (void*)&b2,
                     (void*)&h1b, (void*)&ws };
    hipError_t err = hipLaunchCooperativeKernel((const void*)lstm_fused_kernel,
                                                dim3(256), dim3(512), args,
                                                (int)SMEM_BYTES, stream);
    if (err != hipSuccess) {
        // a rejected cooperative launch fails SILENTLY without this check.
        // 256 blocks at 1/CU are co-resident by resource constraints, so a
        // plain launch preserves the flag protocol.
        hipLaunchKernelGGL(lstm_fused_kernel, dim3(256), dim3(512),
                           (int)SMEM_BYTES, stream,
                           x, W1, U1, b1, W2, U2, b2, h1b, ws);
    }

    const float* h2final = ws + 1024 + SLOT;   // slot 1 = h2[1023]
    hipLaunchKernelGGL(dense_softmax_kernel, dim3(128), dim3(256), 0, stream,
                       h2final, Wd, bd, out);
}